// Round 1
// baseline (324.029 us; speedup 1.0000x reference)
//
#include <hip/hip_runtime.h>
#include <math.h>

// Problem constants
#define S_ 500
#define D_ 768
#define K_ 16
#define R_ 256
#define P_ 64

#define TILE 64
#define KT 16
#define LDSS 68   // LDS row stride (floats): keeps 16B alignment, <=2-way read conflicts

// ---------------------------------------------------------------------------
// Kernel 1: proj[s][k][e] = sum_d WE[s][d] * W[d][k][e]
// Plain GEMM: C[M=500][N=12288] = A[500][768] * B[768][12288], all row-major.
// ---------------------------------------------------------------------------
__global__ __launch_bounds__(256) void gemm_proj(const float* __restrict__ A,
                                                 const float* __restrict__ B,
                                                 float* __restrict__ C) {
  const int M = S_, N = K_ * D_, Kd = D_;
  __shared__ float As[KT * LDSS];
  __shared__ float Bs[KT * LDSS];
  const int t = threadIdx.x;
  const int tx = t & 15, ty = t >> 4;
  const int row0 = blockIdx.y * TILE, col0 = blockIdx.x * TILE;

  float acc[4][4];
#pragma unroll
  for (int i = 0; i < 4; i++)
#pragma unroll
    for (int j = 0; j < 4; j++) acc[i][j] = 0.f;

  const int am = t >> 2, akq = (t & 3) * 4;   // A loader: row am, k-quad akq
  const int bk = t >> 4, bnq = (t & 15) * 4;  // B loader: k-row bk, col-quad bnq

  for (int k0 = 0; k0 < Kd; k0 += KT) {
    float4 av = make_float4(0.f, 0.f, 0.f, 0.f);
    if (row0 + am < M) av = *(const float4*)(A + (size_t)(row0 + am) * Kd + k0 + akq);
    float4 bv = *(const float4*)(B + (size_t)(k0 + bk) * N + col0 + bnq);
    __syncthreads();
    As[(akq + 0) * LDSS + am] = av.x;
    As[(akq + 1) * LDSS + am] = av.y;
    As[(akq + 2) * LDSS + am] = av.z;
    As[(akq + 3) * LDSS + am] = av.w;
    *(float4*)(Bs + bk * LDSS + bnq) = bv;
    __syncthreads();
#pragma unroll
    for (int kk = 0; kk < KT; kk++) {
      float4 a = *(const float4*)(As + kk * LDSS + ty * 4);
      float4 b = *(const float4*)(Bs + kk * LDSS + tx * 4);
      acc[0][0] += a.x * b.x; acc[0][1] += a.x * b.y; acc[0][2] += a.x * b.z; acc[0][3] += a.x * b.w;
      acc[1][0] += a.y * b.x; acc[1][1] += a.y * b.y; acc[1][2] += a.y * b.z; acc[1][3] += a.y * b.w;
      acc[2][0] += a.z * b.x; acc[2][1] += a.z * b.y; acc[2][2] += a.z * b.z; acc[2][3] += a.z * b.w;
      acc[3][0] += a.w * b.x; acc[3][1] += a.w * b.y; acc[3][2] += a.w * b.z; acc[3][3] += a.w * b.w;
    }
  }
#pragma unroll
  for (int i = 0; i < 4; i++) {
    int r = row0 + ty * 4 + i;
    if (r < M) {
      *(float4*)(C + (size_t)r * N + col0 + tx * 4) =
          make_float4(acc[i][0], acc[i][1], acc[i][2], acc[i][3]);
    }
  }
}

// ---------------------------------------------------------------------------
// Kernel 2: G[s1][s2][k] = sum_e proj[s1][k][e] * WE[s2][e]
// GEMM: M=8000 rows = (s1,k), N=500 cols = s2, Kd=768; B = WE^T.
// Epilogue scatters into [s1][s2][16] layout (contiguous k per (s1,s2)).
// ---------------------------------------------------------------------------
__global__ __launch_bounds__(256) void gemm_G(const float* __restrict__ A,   // proj2d [8000][768]
                                              const float* __restrict__ WE,  // [500][768]
                                              float* __restrict__ G) {
  const int M = S_ * K_, N = S_, Kd = D_;
  __shared__ float As[KT * LDSS];
  __shared__ float Bs[KT * LDSS];
  const int t = threadIdx.x;
  const int tx = t & 15, ty = t >> 4;
  const int row0 = blockIdx.y * TILE, col0 = blockIdx.x * TILE;

  float acc[4][4];
#pragma unroll
  for (int i = 0; i < 4; i++)
#pragma unroll
    for (int j = 0; j < 4; j++) acc[i][j] = 0.f;

  const int am = t >> 2, akq = (t & 3) * 4;   // A loader
  const int bn = t >> 2, beq = (t & 3) * 4;   // B loader: col bn (s2), e-quad beq

  for (int k0 = 0; k0 < Kd; k0 += KT) {
    float4 av = make_float4(0.f, 0.f, 0.f, 0.f);
    if (row0 + am < M) av = *(const float4*)(A + (size_t)(row0 + am) * Kd + k0 + akq);
    float4 bv = make_float4(0.f, 0.f, 0.f, 0.f);
    if (col0 + bn < N) bv = *(const float4*)(WE + (size_t)(col0 + bn) * Kd + k0 + beq);
    __syncthreads();
    As[(akq + 0) * LDSS + am] = av.x;
    As[(akq + 1) * LDSS + am] = av.y;
    As[(akq + 2) * LDSS + am] = av.z;
    As[(akq + 3) * LDSS + am] = av.w;
    Bs[(beq + 0) * LDSS + bn] = bv.x;
    Bs[(beq + 1) * LDSS + bn] = bv.y;
    Bs[(beq + 2) * LDSS + bn] = bv.z;
    Bs[(beq + 3) * LDSS + bn] = bv.w;
    __syncthreads();
#pragma unroll
    for (int kk = 0; kk < KT; kk++) {
      float4 a = *(const float4*)(As + kk * LDSS + ty * 4);
      float4 b = *(const float4*)(Bs + kk * LDSS + tx * 4);
      acc[0][0] += a.x * b.x; acc[0][1] += a.x * b.y; acc[0][2] += a.x * b.z; acc[0][3] += a.x * b.w;
      acc[1][0] += a.y * b.x; acc[1][1] += a.y * b.y; acc[1][2] += a.y * b.z; acc[1][3] += a.y * b.w;
      acc[2][0] += a.z * b.x; acc[2][1] += a.z * b.y; acc[2][2] += a.z * b.z; acc[2][3] += a.z * b.w;
      acc[3][0] += a.w * b.x; acc[3][1] += a.w * b.y; acc[3][2] += a.w * b.z; acc[3][3] += a.w * b.w;
    }
  }
  // rows mrow..mrow+3 share s1 (mrow is 4-aligned within a 16-block)
  const int mrow = row0 + ty * 4;
  const int s1 = mrow >> 4;
  const int kq = mrow & 15;
#pragma unroll
  for (int j = 0; j < 4; j++) {
    int s2 = col0 + tx * 4 + j;
    if (s2 < N) {
      *(float4*)(G + (((size_t)s1 * S_ + s2) << 4) + kq) =
          make_float4(acc[0][j], acc[1][j], acc[2][j], acc[3][j]);
    }
  }
}

// ---------------------------------------------------------------------------
// Kernel 3: out[r][k] = logsumexp over valid (p,q) of G[idx1[r,p]][idx2[r,q]][k]
// One block per r. Masks are prefix rectangles -> iterate len1*len2 pairs only.
// ---------------------------------------------------------------------------
__global__ __launch_bounds__(256) void lse_kernel(const float* __restrict__ G,
                                                  const int* __restrict__ idx1,
                                                  const int* __restrict__ idx2,
                                                  const float* __restrict__ mask1,
                                                  const float* __restrict__ mask2,
                                                  float* __restrict__ out) {
  const int r = blockIdx.x;
  const int tid = threadIdx.x;
  __shared__ int b1[P_], b2[P_];
  __shared__ int s_len1, s_len2;
  __shared__ float wm[4][K_], wsum[4][K_];

  if (tid < 64) {
    float mv = mask1[r * P_ + tid];
    unsigned long long bal = __ballot(mv > 0.5f);
    if (tid == 0) s_len1 = (int)__popcll(bal);
    b1[tid] = idx1[r * P_ + tid] * (S_ * K_);
  } else if (tid < 128) {
    int q = tid - 64;
    float mv = mask2[r * P_ + q];
    unsigned long long bal = __ballot(mv > 0.5f);
    if (q == 0) s_len2 = (int)__popcll(bal);
    b2[q] = idx2[r * P_ + q] * K_;
  }
  __syncthreads();
  const int len1 = s_len1, len2 = s_len2;
  const int total = len1 * len2;

  float m[K_], s[K_];
#pragma unroll
  for (int k = 0; k < K_; k++) { m[k] = -3.0e38f; s[k] = 0.f; }

  for (int i = tid; i < total; i += 256) {
    int p = i / len2;
    int q = i - p * len2;
    const float4* g4 = (const float4*)(G + b1[p] + b2[q]);
    float4 z0 = g4[0], z1 = g4[1], z2 = g4[2], z3 = g4[3];
    float z[K_] = {z0.x, z0.y, z0.z, z0.w, z1.x, z1.y, z1.z, z1.w,
                   z2.x, z2.y, z2.z, z2.w, z3.x, z3.y, z3.z, z3.w};
#pragma unroll
    for (int k = 0; k < K_; k++) {
      float zk = z[k];
      float M2 = fmaxf(m[k], zk);
      s[k] = s[k] * __expf(m[k] - M2) + __expf(zk - M2);
      m[k] = M2;
    }
  }

  // wave-level butterfly reduce (wave = 64)
#pragma unroll
  for (int off = 1; off < 64; off <<= 1) {
#pragma unroll
    for (int k = 0; k < K_; k++) {
      float mo = __shfl_xor(m[k], off, 64);
      float so = __shfl_xor(s[k], off, 64);
      float M2 = fmaxf(m[k], mo);
      s[k] = s[k] * __expf(m[k] - M2) + so * __expf(mo - M2);
      m[k] = M2;
    }
  }
  const int wave = tid >> 6, lane = tid & 63;
  if (lane == 0) {
#pragma unroll
    for (int k = 0; k < K_; k++) { wm[wave][k] = m[k]; wsum[wave][k] = s[k]; }
  }
  __syncthreads();
  if (tid < K_) {
    float M = -3.0e38f, Ssum = 0.f;
#pragma unroll
    for (int w = 0; w < 4; w++) {
      float mo = wm[w][tid], so = wsum[w][tid];
      float M2 = fmaxf(M, mo);
      Ssum = Ssum * __expf(M - M2) + so * __expf(mo - M2);
      M = M2;
    }
    out[r * K_ + tid] = M + __logf(Ssum);
  }
}

// ---------------------------------------------------------------------------
extern "C" void kernel_launch(void* const* d_in, const int* in_sizes, int n_in,
                              void* d_out, int out_size, void* d_ws, size_t ws_size,
                              hipStream_t stream) {
  const float* WE    = (const float*)d_in[0];  // [500][768]
  const float* W     = (const float*)d_in[1];  // [768][16][768]
  const int*   idx1  = (const int*)d_in[2];    // [256][64]
  const int*   idx2  = (const int*)d_in[3];    // [256][64]
  const float* mask1 = (const float*)d_in[4];  // [256][64]
  const float* mask2 = (const float*)d_in[5];  // [256][64]
  float* out = (float*)d_out;                  // [256][16]

  float* proj = (float*)d_ws;                  // [500][16][768] = 8000x768
  float* G    = proj + (size_t)(S_ * K_) * D_; // [500][500][16]

  // proj = WE @ W   (M=500, N=12288, K=768)
  gemm_proj<<<dim3((K_ * D_) / TILE, (S_ + TILE - 1) / TILE), 256, 0, stream>>>(WE, W, proj);
  // G = proj2d @ WE^T  (M=8000, N=500, K=768), scattered to [s1][s2][k]
  gemm_G<<<dim3((S_ + TILE - 1) / TILE, (S_ * K_) / TILE), 256, 0, stream>>>(proj, WE, G);
  // masked logsumexp gather
  lse_kernel<<<R_, 256, 0, stream>>>(G, idx1, idx2, mask1, mask2, out);
}

// Round 2
// 151.464 us; speedup vs baseline: 2.1393x; 2.1393x over previous
//
#include <hip/hip_runtime.h>
#include <math.h>

// Problem constants
#define S_ 500
#define D_ 768
#define K_ 16
#define R_ 256
#define P_ 64

typedef unsigned short ushort_t;
typedef __attribute__((ext_vector_type(8))) short short8;   // 8 x bf16 (4 VGPRs)
typedef __attribute__((ext_vector_type(4))) float floatx4;  // MFMA accumulator

__device__ inline ushort_t f2bf(float x) {  // fp32 -> bf16, round-nearest-even
  unsigned int u = __float_as_uint(x);
  u += 0x7fffu + ((u >> 16) & 1u);
  return (ushort_t)(u >> 16);
}

#define GLD_LDS16(g, l)                                                        \
  __builtin_amdgcn_global_load_lds(                                            \
      (const __attribute__((address_space(1))) void*)(g),                      \
      (__attribute__((address_space(3))) void*)(l), 16, 0, 0)

// ---------------------------------------------------------------------------
// convert_we: WE fp32 [500][768] -> WEb bf16 [512][768], rows 500..511 = 0
// ---------------------------------------------------------------------------
__global__ __launch_bounds__(256) void convert_we(const float* __restrict__ WE,
                                                  ushort_t* __restrict__ WEb) {
  int gid = blockIdx.x * 256 + threadIdx.x;  // 98304 threads, 4 elems each
  int row = gid / 192;                       // 192 float4 per row
  ushort4 o = {0, 0, 0, 0};
  if (row < S_) {
    float4 v = *(const float4*)(WE + (size_t)gid * 4);
    o.x = f2bf(v.x); o.y = f2bf(v.y); o.z = f2bf(v.z); o.w = f2bf(v.w);
  }
  *(ushort4*)(WEb + (size_t)gid * 4) = o;
}

// ---------------------------------------------------------------------------
// transpose_w: W fp32 [768][12288] -> Wt bf16 [12288 rows (k,e)][768 cols d]
// ---------------------------------------------------------------------------
__global__ __launch_bounds__(256) void transpose_w(const float* __restrict__ W,
                                                   ushort_t* __restrict__ Wt) {
  __shared__ float tile[32][33];
  const int t = threadIdx.x;
  const int n0 = blockIdx.x * 32, d0 = blockIdx.y * 32;
  const int r = t >> 3, c4 = (t & 7) * 4;
  float4 v = *(const float4*)(W + (size_t)(d0 + r) * 12288 + n0 + c4);
  tile[r][c4 + 0] = v.x; tile[r][c4 + 1] = v.y;
  tile[r][c4 + 2] = v.z; tile[r][c4 + 3] = v.w;
  __syncthreads();
  ushort4 o;
  o.x = f2bf(tile[c4 + 0][r]); o.y = f2bf(tile[c4 + 1][r]);
  o.z = f2bf(tile[c4 + 2][r]); o.w = f2bf(tile[c4 + 3][r]);
  *(ushort4*)(Wt + (size_t)(n0 + r) * 768 + d0 + c4) = o;
}

// ---------------------------------------------------------------------------
// mm_bt<MODE>: C[M][N] = A[M][768] * B[N][768]^T, bf16 in, fp32 MFMA accum.
// m97 structure: 128x128 tile, BK=32, 4 waves, global_load_lds width 16.
// MODE 0: C = proj bf16 [512][12288] (== proj2d [8192][768] in memory)
// MODE 1: C scattered fp32 into G[s1][s2][16] (m=(s1,k), n=s2), guarded <500
// ---------------------------------------------------------------------------
template <int MODE>
__global__ __launch_bounds__(256) void mm_bt(const ushort_t* __restrict__ A,
                                             const ushort_t* __restrict__ Bm,
                                             void* __restrict__ Cout) {
  __shared__ ushort_t As[128 * 32];  // [row m][k] bf16, 8 KB
  __shared__ ushort_t Bs[128 * 32];  // [row n][k] bf16, 8 KB
  const int tid = threadIdx.x;
  const int wave = tid >> 6, lane = tid & 63;
  const int m0 = blockIdx.y * 128, n0 = blockIdx.x * 128;
  const int wm = (wave & 1) * 64, wn = (wave >> 1) * 64;  // wave's 64x64 quadrant
  const int col = lane & 15, quad = lane >> 4;

  floatx4 acc[4][4];
#pragma unroll
  for (int i = 0; i < 4; i++)
#pragma unroll
    for (int j = 0; j < 4; j++)
#pragma unroll
      for (int e = 0; e < 4; e++) acc[i][j][e] = 0.f;

  // staging addresses: wave covers rows [wave*32, wave*32+32), 2 issues of 16 rows
  const int srow = wave * 32 + (lane >> 2);  // +0 / +16 per issue
  const int scol = (lane & 3) * 8;           // 8 bf16 = 16 B per lane

  for (int k0 = 0; k0 < D_; k0 += 32) {
    const ushort_t* ga = A + (size_t)(m0 + srow) * D_ + k0 + scol;
    const ushort_t* gb = Bm + (size_t)(n0 + srow) * D_ + k0 + scol;
    __syncthreads();  // previous iter's LDS reads done before overwrite
    GLD_LDS16(ga, &As[(wave * 32) * 32]);
    GLD_LDS16(ga + 16 * D_, &As[(wave * 32 + 16) * 32]);
    GLD_LDS16(gb, &Bs[(wave * 32) * 32]);
    GLD_LDS16(gb + 16 * D_, &Bs[(wave * 32 + 16) * 32]);
    __syncthreads();  // staging complete (vmcnt drained by barrier semantics)

    short8 a[4], b[4];
#pragma unroll
    for (int i = 0; i < 4; i++)
      a[i] = *(const short8*)&As[(wm + i * 16 + col) * 32 + quad * 8];
#pragma unroll
    for (int j = 0; j < 4; j++)
      b[j] = *(const short8*)&Bs[(wn + j * 16 + col) * 32 + quad * 8];
#pragma unroll
    for (int i = 0; i < 4; i++)
#pragma unroll
      for (int j = 0; j < 4; j++)
        acc[i][j] = __builtin_amdgcn_mfma_f32_16x16x32_bf16(a[i], b[j], acc[i][j], 0, 0, 0);
  }

  if (MODE == 0) {
    // proj bf16 [512][12288]; D row = m0+wm+i*16+quad*4+r, col n
    ushort_t* C = (ushort_t*)Cout;
#pragma unroll
    for (int i = 0; i < 4; i++) {
      int mb = m0 + wm + i * 16 + quad * 4;
#pragma unroll
      for (int j = 0; j < 4; j++) {
        int n = n0 + wn + j * 16 + col;
        C[(size_t)(mb + 0) * 12288 + n] = f2bf(acc[i][j][0]);
        C[(size_t)(mb + 1) * 12288 + n] = f2bf(acc[i][j][1]);
        C[(size_t)(mb + 2) * 12288 + n] = f2bf(acc[i][j][2]);
        C[(size_t)(mb + 3) * 12288 + n] = f2bf(acc[i][j][3]);
      }
    }
  } else {
    // G[s1][s2][16] fp32: m = (s1,k); 16x16 m-tile is one s1, k = quad*4+reg
    float* G = (float*)Cout;
#pragma unroll
    for (int i = 0; i < 4; i++) {
      int s1 = (m0 + wm + i * 16) >> 4;
#pragma unroll
      for (int j = 0; j < 4; j++) {
        int s2 = n0 + wn + j * 16 + col;
        if (s1 < S_ && s2 < S_)
          *(floatx4*)(G + (((size_t)s1 * S_ + s2) << 4) + quad * 4) = acc[i][j];
      }
    }
  }
}

// ---------------------------------------------------------------------------
// lse_kernel: out[r][k] = logsumexp over valid (p,q) of G[idx1[r,p]][idx2[r,q]][k]
// ---------------------------------------------------------------------------
__global__ __launch_bounds__(256) void lse_kernel(const float* __restrict__ G,
                                                  const int* __restrict__ idx1,
                                                  const int* __restrict__ idx2,
                                                  const float* __restrict__ mask1,
                                                  const float* __restrict__ mask2,
                                                  float* __restrict__ out) {
  const int r = blockIdx.x;
  const int tid = threadIdx.x;
  __shared__ int b1[P_], b2[P_];
  __shared__ int s_len1, s_len2;
  __shared__ float wm[4][K_], wsum[4][K_];

  if (tid < 64) {
    float mv = mask1[r * P_ + tid];
    unsigned long long bal = __ballot(mv > 0.5f);
    if (tid == 0) s_len1 = (int)__popcll(bal);
    b1[tid] = idx1[r * P_ + tid] * (S_ * K_);
  } else if (tid < 128) {
    int q = tid - 64;
    float mv = mask2[r * P_ + q];
    unsigned long long bal = __ballot(mv > 0.5f);
    if (q == 0) s_len2 = (int)__popcll(bal);
    b2[q] = idx2[r * P_ + q] * K_;
  }
  __syncthreads();
  const int len1 = s_len1, len2 = s_len2;
  const int total = len1 * len2;

  float m[K_], s[K_];
#pragma unroll
  for (int k = 0; k < K_; k++) { m[k] = -3.0e38f; s[k] = 0.f; }

  for (int i = tid; i < total; i += 256) {
    int p = i / len2;
    int q = i - p * len2;
    const float4* g4 = (const float4*)(G + b1[p] + b2[q]);
    float4 z0 = g4[0], z1 = g4[1], z2 = g4[2], z3 = g4[3];
    float z[K_] = {z0.x, z0.y, z0.z, z0.w, z1.x, z1.y, z1.z, z1.w,
                   z2.x, z2.y, z2.z, z2.w, z3.x, z3.y, z3.z, z3.w};
#pragma unroll
    for (int k = 0; k < K_; k++) {
      float zk = z[k];
      float M2 = fmaxf(m[k], zk);
      s[k] = s[k] * __expf(m[k] - M2) + __expf(zk - M2);
      m[k] = M2;
    }
  }

#pragma unroll
  for (int off = 1; off < 64; off <<= 1) {
#pragma unroll
    for (int k = 0; k < K_; k++) {
      float mo = __shfl_xor(m[k], off, 64);
      float so = __shfl_xor(s[k], off, 64);
      float M2 = fmaxf(m[k], mo);
      s[k] = s[k] * __expf(m[k] - M2) + so * __expf(mo - M2);
      m[k] = M2;
    }
  }
  const int wave = tid >> 6, lane = tid & 63;
  if (lane == 0) {
#pragma unroll
    for (int k = 0; k < K_; k++) { wm[wave][k] = m[k]; wsum[wave][k] = s[k]; }
  }
  __syncthreads();
  if (tid < K_) {
    float M = -3.0e38f, Ssum = 0.f;
#pragma unroll
    for (int w = 0; w < 4; w++) {
      float mo = wm[w][tid], so = wsum[w][tid];
      float M2 = fmaxf(M, mo);
      Ssum = Ssum * __expf(M - M2) + so * __expf(mo - M2);
      M = M2;
    }
    out[r * K_ + tid] = M + __logf(Ssum);
  }
}

// ---------------------------------------------------------------------------
extern "C" void kernel_launch(void* const* d_in, const int* in_sizes, int n_in,
                              void* d_out, int out_size, void* d_ws, size_t ws_size,
                              hipStream_t stream) {
  const float* WE    = (const float*)d_in[0];  // [500][768]
  const float* W     = (const float*)d_in[1];  // [768][16][768]
  const int*   idx1  = (const int*)d_in[2];
  const int*   idx2  = (const int*)d_in[3];
  const float* mask1 = (const float*)d_in[4];
  const float* mask2 = (const float*)d_in[5];
  float* out = (float*)d_out;                  // [256][16]

  // workspace: WEb [512][768] bf16 | Wt [12288][768] bf16 |
  //            projb [512][12288] bf16 (== [8192][768]) | G [500][500][16] f32
  ushort_t* WEb   = (ushort_t*)d_ws;
  ushort_t* Wt    = WEb + (size_t)512 * 768;
  ushort_t* projb = Wt + (size_t)12288 * 768;
  float*    G     = (float*)(projb + (size_t)8192 * 768);
  // total: 32,243,712 B + 16,000,000 B = 48.2 MB (16B-aligned throughout)

  convert_we<<<384, 256, 0, stream>>>(WE, WEb);
  transpose_w<<<dim3(384, 24), 256, 0, stream>>>(W, Wt);
  // proj[s][(k,e)] = WEb @ Wt^T : M=512, N=12288
  mm_bt<0><<<dim3(96, 4), 256, 0, stream>>>(WEb, Wt, (void*)projb);
  // G[(s1,k)][s2] = projb @ WEb^T : M=8192, N=512, scattered to [s1][s2][16]
  mm_bt<1><<<dim3(4, 64), 256, 0, stream>>>(projb, WEb, (void*)G);
  lse_kernel<<<R_, 256, 0, stream>>>(G, idx1, idx2, mask1, mask2, out);
}